// Round 9
// baseline (522.800 us; speedup 1.0000x reference)
//
#include <hip/hip_runtime.h>

// ============================================================================
// TransformerSubsetAggregator on MI355X (gfx950) — round 20
// vs r19 (513.9us, k_ff 93.5us, banked): remaining X fp32 traffic cut. k_fin
// re-reads all 67MB of X just to masked-pool 8 rows/chain, but those exact
// values are in k_oproj's registers ('old') at store time. r20: k_oproj
// computes the masked chain-pool inline (mask-mul + 3x shfl_xor over the 8
// token-row lanes + one float4 store per (c,it) from lanes r4 in {0,8}) into
// Xpool[8192x256] f32 (8.4MB, dead tail of QKVp region, live k_oproj->k_fin
// only). X becomes dead after k_oproj; k_fin reads Xpool+Pxg (30MB total)
// instead of ~94MB. Transient registers only -> no spill risk at (512,4).
// All other kernels byte-identical to r19.
// Pipeline: k_prep | k_sel(+LN1->H1p) | k_qkv | k_attn | k_oproj(+LN2,+Xpool)
//           | k_ff x2 halves(->Pxg) | k_fin(->Fp) | memset(out) | k_headmlp
// ============================================================================

#define DIM   256
#define LSEQ  128
#define KTOK  8

typedef __bf16 bf16x8 __attribute__((ext_vector_type(8)));
typedef float  f32x4  __attribute__((ext_vector_type(4)));
typedef unsigned short u16x8 __attribute__((ext_vector_type(8)));

__device__ __forceinline__ f32x4 mfma16(bf16x8 a, bf16x8 b, f32x4 c) {
  // D[m][n] = sum_k A[m][k]B[n][k]; lane map (both ops): idx=lane&15,
  // k=(lane>>4)*8+j. D: col(lane&15)=n, row=(lane>>4)*4+reg=m.
  return __builtin_amdgcn_mfma_f32_16x16x32_bf16(a, b, c, 0, 0, 0);
}

// HW RNE f32->bf16 (v_cvt; compiler pairs adjacent ones into v_cvt_pk_bf16_f32)
__device__ __forceinline__ unsigned short f2bf(float f) {
  union { __bf16 h; unsigned short u; } cv;
  cv.h = (__bf16)f;
  return cv.u;
}

__device__ __forceinline__ unsigned pack2bf(float a, float b) {
  union { __bf16 h2[2]; unsigned u; } cv;
  cv.h2[0] = (__bf16)a; cv.h2[1] = (__bf16)b;
  return cv.u;
}

// tanh-form gelu (~10 VALU ops); dev from exact ~1e-3 << bf16 rounding.
__device__ __forceinline__ float gelu_fast(float x) {
  const float x2 = x * x;
  const float y = x * __builtin_fmaf(0.0356774081f, x2, 0.7978845608f);
  const float e = __expf(2.f * y);
  const float r = __builtin_amdgcn_rcpf(e + 1.f);
  const float t = __builtin_fmaf(-2.f, r, 1.f);       // tanh(y)
  return 0.5f * x * (1.f + t);
}

// butterfly sum over the 8 token-lanes (lane bits 0..2)
__device__ __forceinline__ float rsum8(float v) {
  v += __shfl_xor(v, 1);
  v += __shfl_xor(v, 2);
  v += __shfl_xor(v, 4);
  return v;
}

union U4 { unsigned u[4]; bf16x8 v; };

// ---- async global->LDS, 16B/lane; lds base wave-uniform, HW adds lane*16.
__device__ __forceinline__ void gload16(const unsigned short* g, unsigned short* lds_uniform) {
  auto gp = reinterpret_cast<const __attribute__((address_space(1))) unsigned*>(
      reinterpret_cast<uintptr_t>(g));
  auto lp = reinterpret_cast<__attribute__((address_space(3))) unsigned*>(
      (unsigned)reinterpret_cast<uintptr_t>(lds_uniform));
  __builtin_amdgcn_global_load_lds(gp, lp, 16, 0, 0);
}

// ---- 32KB chunk staging: register prefetch + LDS commit (512-thr kernels)
struct Stage32 { u16x8 r[4]; };
__device__ __forceinline__ void stage_load(Stage32& st, const unsigned short* __restrict__ g, int tid) {
  #pragma unroll
  for (int i = 0; i < 4; ++i) st.r[i] = *(const u16x8*)&g[(tid + i * 512) * 8];
}
__device__ __forceinline__ void stage_commit(const Stage32& st, unsigned short* l, int tid) {
  #pragma unroll
  for (int i = 0; i < 4; ++i) *(u16x8*)&l[(tid + i * 512) * 8] = st.r[i];
}

// ---------------------------------------------------------------------------
// k_prep: pack weights fp32 -> bf16 fragment-major.
// ---------------------------------------------------------------------------
__device__ __forceinline__ void pack_region(
    const float* __restrict__ src, unsigned short* __restrict__ dst,
    int g, int KC, int Ksrc, int Klim)
{
  const int ln = g & 63;
  const int t = g >> 6;
  const int s = t % KC;
  const int ntile = t / KC;
  const int row = ntile * 16 + (ln & 15);
  const int c0 = s * 32 + (ln >> 4) * 8;
  u16x8 o;
  #pragma unroll
  for (int j = 0; j < 8; ++j) {
    float val = (c0 + j < Klim) ? src[(long)row * Ksrc + c0 + j] : 0.f;
    o[j] = f2bf(val);
  }
  *(u16x8*)&dst[(long)g * 8] = o;
}

__device__ __forceinline__ void pack_region_kmaj(
    const float* __restrict__ src, unsigned short* __restrict__ dst,
    int g, int NT, int Ksrc)
{
  const int ln = g & 63;
  const int t = g >> 6;
  const int ntile = t % NT;
  const int s = t / NT;
  const int row = ntile * 16 + (ln & 15);
  const int c0 = s * 32 + (ln >> 4) * 8;
  u16x8 o;
  #pragma unroll
  for (int j = 0; j < 8; ++j) o[j] = f2bf(src[(long)row * Ksrc + c0 + j]);
  *(u16x8*)&dst[(long)g * 8] = o;
}

#define PREP_GROUPS 172032
__global__ __launch_bounds__(256) void k_prep(
    const float* __restrict__ wqkv, const float* __restrict__ wo,
    const float* __restrict__ wff1, const float* __restrict__ wff2,
    const float* __restrict__ wout1, const float* __restrict__ wout2,
    unsigned short* __restrict__ oq, unsigned short* __restrict__ oo,
    unsigned short* __restrict__ of1, unsigned short* __restrict__ of2,
    unsigned short* __restrict__ oo1, unsigned short* __restrict__ oo2)
{
  int g = blockIdx.x * 256 + threadIdx.x;
  if (g < 24576) { pack_region(wqkv, oq, g, 8, 256, 256); return; }     // n-major
  g -= 24576;
  if (g < 8192)  { pack_region(wo, oo, g, 8, 256, 256); return; }       // n-major
  g -= 8192;
  if (g < 32768) { pack_region(wff1, of1, g, 8, 256, 256); return; }    // n-major (f-chunked)
  g -= 32768;
  if (g < 32768) { pack_region_kmaj(wff2, of2, g, 16, 1024); return; }  // k-major
  g -= 32768;
  if (g < 40960) { pack_region(wout1, oo1, g, 10, 257, 257); return; }  // n-major (f-chunked)
  g -= 40960;
  if (g < 32768) { pack_region_kmaj(wout2, oo2, g, 16, 1024); }         // k-major
}

// ---------------------------------------------------------------------------
// k_sel: top-8 (lax.top_k ties: value desc, idx asc), sort picked idx asc,
// gather v + pos_embed -> X fp32 (row-major), fused LN1 -> H1 PACKED bf16.
// ---------------------------------------------------------------------------
__global__ __launch_bounds__(256) void k_sel(
    const float* __restrict__ v, const int* __restrict__ batch_idx,
    const int* __restrict__ mask, const float* __restrict__ rank_scores,
    const float* __restrict__ pos_embed,
    const float* __restrict__ ln1g, const float* __restrict__ ln1b,
    float* __restrict__ X, unsigned short* __restrict__ H1p,
    int* __restrict__ NPICK)
{
  const int c = blockIdx.x;
  const int tid = threadIdx.x;
  __shared__ int s_mem[KTOK];
  __shared__ int s_np;

  if (tid < 64) {
    const int l = tid;
    unsigned long long key[2];
    #pragma unroll
    for (int t = 0; t < 2; ++t) {
      int p = l + 64 * t;
      int mk = mask[c * LSEQ + p];
      float s = rank_scores[c * LSEQ + p];
      unsigned u = __float_as_uint(s);
      u = (u & 0x80000000u) ? ~u : (u | 0x80000000u);
      unsigned long long kk =
          ((unsigned long long)u << 32) | (unsigned long long)(0xFFFFFFFFu - (unsigned)p);
      key[t] = mk ? kk : 0ull;
    }
    int w[KTOK];
    #pragma unroll
    for (int r = 0; r < KTOK; ++r) w[r] = 0x7FFFFFFF;
    int np = 0;
    for (int r = 0; r < KTOK; ++r) {
      unsigned long long best = key[0] > key[1] ? key[0] : key[1];
      for (int off = 32; off > 0; off >>= 1) {
        unsigned long long o = __shfl_xor(best, off, 64);
        if (o > best) best = o;
      }
      if (best == 0ull) break;
      int idx = (int)(0xFFFFFFFFu - (unsigned)(best & 0xFFFFFFFFull));
      w[np++] = idx;
      if (key[0] == best) key[0] = 0ull;
      if (key[1] == best) key[1] = 0ull;
    }
    #pragma unroll
    for (int a = 0; a < KTOK - 1; ++a)
      #pragma unroll
      for (int b2 = 0; b2 < KTOK - 1 - a; ++b2) {
        int x0 = w[b2], x1 = w[b2 + 1];
        w[b2] = min(x0, x1); w[b2 + 1] = max(x0, x1);
      }
    if (l < KTOK) s_mem[l] = (l < np) ? batch_idx[c * LSEQ + w[l]] : -1;
    if (l == 0) { s_np = np; NPICK[c] = np; }
  }
  __syncthreads();

  const int np = s_np;
  const int j = tid >> 5, q = tid & 31;     // 32 threads/token, 8 cols each
  const int r = s_mem[j];
  const float4* v4  = (const float4*)v;
  const float4* pe4 = (const float4*)pos_embed;
  float4* X4 = (float4*)X;

  float4 xv[2];                              // cols q*8 .. q*8+7
  #pragma unroll
  for (int rep = 0; rep < 2; ++rep) {
    const int f = 2 * q + rep;
    float4 pe = pe4[j * 64 + f];
    float4 val = make_float4(0.f, 0.f, 0.f, 0.f);
    if (j < np) val = v4[(long)r * 64 + f];
    xv[rep].x = val.x + pe.x; xv[rep].y = val.y + pe.y;
    xv[rep].z = val.z + pe.z; xv[rep].w = val.w + pe.w;
    X4[((long)c * KTOK + j) * 64 + f] = xv[rep];
  }
  float sum = 0.f, ss = 0.f;
  #pragma unroll
  for (int rep = 0; rep < 2; ++rep) {
    sum += xv[rep].x + xv[rep].y + xv[rep].z + xv[rep].w;
    ss  += xv[rep].x * xv[rep].x + xv[rep].y * xv[rep].y
         + xv[rep].z * xv[rep].z + xv[rep].w * xv[rep].w;
  }
  #pragma unroll
  for (int off = 1; off <= 16; off <<= 1) {
    sum += __shfl_xor(sum, off); ss += __shfl_xor(ss, off);
  }
  const float mu = sum * (1.f / 256.f);
  const float var = ss * (1.f / 256.f) - mu * mu;
  const float rstd = rsqrtf(var + 1e-5f);
  const int t = c * KTOK + j;
  const int mtile = t >> 4, lr = t & 15;
  const int s = q >> 2, lq = q & 3;
  u16x8 o;
  const int col = q * 8;
  o[0] = f2bf((xv[0].x - mu) * rstd * ln1g[col + 0] + ln1b[col + 0]);
  o[1] = f2bf((xv[0].y - mu) * rstd * ln1g[col + 1] + ln1b[col + 1]);
  o[2] = f2bf((xv[0].z - mu) * rstd * ln1g[col + 2] + ln1b[col + 2]);
  o[3] = f2bf((xv[0].w - mu) * rstd * ln1g[col + 3] + ln1b[col + 3]);
  o[4] = f2bf((xv[1].x - mu) * rstd * ln1g[col + 4] + ln1b[col + 4]);
  o[5] = f2bf((xv[1].y - mu) * rstd * ln1g[col + 5] + ln1b[col + 5]);
  o[6] = f2bf((xv[1].z - mu) * rstd * ln1g[col + 6] + ln1b[col + 6]);
  o[7] = f2bf((xv[1].w - mu) * rstd * ln1g[col + 7] + ln1b[col + 7]);
  *(u16x8*)&H1p[((long)(mtile * 8 + s) * 64 + lq * 16 + lr) * 8] = o;
}

// ---------------------------------------------------------------------------
// k_qkv: QKV GEMM, M=65536, N=768, K=256. 512 thr = 8 waves = 128 tokens.
// (r9 config — do not touch: r7/r10 launch-bound changes both spilled.)
// ---------------------------------------------------------------------------
__global__ __launch_bounds__(512, 4) void k_qkv(
    const unsigned short* __restrict__ H1p, unsigned short* __restrict__ QKVp,
    const unsigned short* __restrict__ wqp, const float* __restrict__ bqkv)
{
  __shared__ unsigned short buf[16384];      // 32 KB
  __shared__ unsigned short sT[8 * 16 * 72]; // per-wave 16 tok x 64 col (+8 pad)
  const int tid = threadIdx.x;
  const int wv = tid >> 6, ln = tid & 63;
  const int lr = ln & 15, lq = ln >> 4;
  const int mtile = blockIdx.x * 8 + wv;
  const f32x4 vzero = {0.f, 0.f, 0.f, 0.f};
  unsigned short* sTw = &sT[wv * 1152];

  bf16x8 af[8];
  #pragma unroll
  for (int s = 0; s < 8; ++s)
    af[s] = *(const bf16x8*)&H1p[((long)(mtile * 8 + s) * 64 + ln) * 8];

  Stage32 st;
  stage_load(st, wqp, tid);
  for (int c = 0; c < 12; ++c) {
    stage_commit(st, buf, tid);
    __syncthreads();
    if (c < 11) stage_load(st, wqp + (c + 1) * 16384, tid);
    f32x4 acc[4];
    #pragma unroll
    for (int nt = 0; nt < 4; ++nt) acc[nt] = vzero;
    #pragma unroll
    for (int s = 0; s < 8; ++s) {
      #pragma unroll
      for (int nt = 0; nt < 4; ++nt) {
        bf16x8 b = *(const bf16x8*)&buf[(nt * 8 + s) * 512 + ln * 8];
        acc[nt] = mfma16(af[s], b, acc[nt]);
      }
    }
    #pragma unroll
    for (int nt = 0; nt < 4; ++nt) {
      const float bias = bqkv[c * 64 + nt * 16 + lr];
      #pragma unroll
      for (int reg = 0; reg < 4; ++reg)
        sTw[(lq * 4 + reg) * 72 + nt * 16 + lr] = f2bf(acc[nt][reg] + bias);
    }
    const int r8 = ln >> 3, cg = ln & 7;
    #pragma unroll
    for (int h = 0; h < 2; ++h) {
      const int tok = h * 8 + r8;
      u16x8 vv = *(const u16x8*)&sTw[tok * 72 + cg * 8];
      *(u16x8*)&QKVp[((long)(mtile * 16 + tok)) * 768 + c * 64 + cg * 8] = vv;
    }
    __syncthreads();
  }
}

// ---------------------------------------------------------------------------
// k_attn: 4 chains (32 tokens)/block, 128 threads. Stages only K+V into LDS
// (33.3KB -> 4 blocks/CU); per-thread Q slice read directly from L2-warm
// QKVp into registers before the barrier.
// ---------------------------------------------------------------------------
#define SKV 520   // 512 + 8

__global__ __launch_bounds__(128) void k_attn(
    const unsigned short* __restrict__ QKVp, const int* __restrict__ NPICK,
    unsigned short* __restrict__ Op)
{
  __shared__ unsigned short sKV[32 * SKV];   // cols 0..255 = K, 256..511 = V
  __shared__ int s_np[4];
  const int tid = threadIdx.x;
  const int blk = blockIdx.x;
  if (tid < 4) s_np[tid] = NPICK[blk * 4 + tid];
  for (int i = tid; i < 2048; i += 128) {    // 16 x u16x8 per thread
    const int r = i >> 6, u = i & 63;
    *(u16x8*)&sKV[r * SKV + u * 8] =
        *(const u16x8*)&QKVp[((long)blk * 32 + r) * 768 + 256 + u * 8];
  }
  const int c = tid >> 5, hh = (tid >> 3) & 3, qi = tid & 7;
  const int qrow = c * 8 + qi;
  bf16x8 qv[8];                              // own Q slice: 128B from global
  #pragma unroll
  for (int dc = 0; dc < 8; ++dc)
    qv[dc] = *(const bf16x8*)&QKVp[((long)blk * 32 + qrow) * 768 + hh * 64 + dc * 8];
  __syncthreads();

  const int natt = max(1, s_np[c]);
  float sc[8];
  #pragma unroll
  for (int j = 0; j < 8; ++j) sc[j] = -1e30f;
  for (int j = 0; j < natt; ++j) {
    float d = 0.f;
    #pragma unroll
    for (int dc = 0; dc < 8; ++dc) {
      bf16x8 kv = *(const bf16x8*)&sKV[(c * 8 + j) * SKV + hh * 64 + dc * 8];
      #pragma unroll
      for (int e = 0; e < 8; ++e) d += (float)qv[dc][e] * (float)kv[e];
    }
    sc[j] = d * 0.125f;
  }
  float mx = -1e30f;
  #pragma unroll
  for (int j = 0; j < 8; ++j) mx = fmaxf(mx, sc[j]);
  float pr[8]; float ssum = 0.f;
  #pragma unroll
  for (int j = 0; j < 8; ++j) {
    float e = (j < natt) ? __expf(sc[j] - mx) : 0.f;
    pr[j] = e; ssum += e;
  }
  const float inv = 1.f / ssum;
  const int t = blk * 32 + qrow;
  const int mt = t >> 4, lrt = t & 15;
  #pragma unroll
  for (int dc = 0; dc < 8; ++dc) {
    float o8[8] = {0.f,0.f,0.f,0.f,0.f,0.f,0.f,0.f};
    for (int j = 0; j < natt; ++j) {
      const float pj = pr[j] * inv;
      bf16x8 vv = *(const bf16x8*)&sKV[(c * 8 + j) * SKV + 256 + hh * 64 + dc * 8];
      #pragma unroll
      for (int e = 0; e < 8; ++e) o8[e] += pj * (float)vv[e];
    }
    u16x8 o;
    #pragma unroll
    for (int e = 0; e < 8; ++e) o[e] = f2bf(o8[e]);
    const int s = hh * 2 + (dc >> 2), lqt = dc & 3;
    *(u16x8*)&Op[((long)(mt * 8 + s) * 64 + lqt * 16 + lrt) * 8] = o;
  }
}

// ---------------------------------------------------------------------------
// k_oproj: X += O @ wo^T + bo, FUSED LN2 -> H2p, FUSED masked X-pool -> Xpool
// (r20: pool computed from 'old' in-register; transient shfl-reduce only, no
// persistent accumulators -> no spill risk at the (512,4) 128-reg ceiling).
// ---------------------------------------------------------------------------
__global__ __launch_bounds__(512, 4) void k_oproj(
    const unsigned short* __restrict__ Op, float* __restrict__ X,
    const unsigned short* __restrict__ wop, const float* __restrict__ bo,
    const float* __restrict__ ln2g, const float* __restrict__ ln2b,
    unsigned short* __restrict__ H2p,
    const int* __restrict__ NPICK, float* __restrict__ Xpool)
{
  __shared__ unsigned short buf[16384];
  __shared__ float sTf[8 * 16 * 68];         // per-wave 16 tok x 64 col (+4 pad)
  const int tid = threadIdx.x;
  const int wv = tid >> 6, ln = tid & 63;
  const int lr = ln & 15, lq = ln >> 4;
  const int mtile = blockIdx.x * 8 + wv;
  const f32x4 vzero = {0.f, 0.f, 0.f, 0.f};
  float* sTw = &sTf[wv * 1088];

  bf16x8 af[8];
  #pragma unroll
  for (int s = 0; s < 8; ++s)
    af[s] = *(const bf16x8*)&Op[((long)(mtile * 8 + s) * 64 + ln) * 8];

  const int r4 = ln >> 2, g4 = ln & 3;
  // row-mask for the masked pool: this lane's row r4 belongs to chain
  // mtile*2 + (r4>>3); row-in-chain = r4&7.
  const int pch = mtile * 2 + (r4 >> 3);
  const float mkrow = ((r4 & 7) < NPICK[pch]) ? 1.f : 0.f;
  float lsum = 0.f, lss = 0.f;               // partial LN sums for row r4

  Stage32 st;
  stage_load(st, wop, tid);
  for (int c = 0; c < 4; ++c) {
    stage_commit(st, buf, tid);
    __syncthreads();
    if (c < 3) stage_load(st, wop + (c + 1) * 16384, tid);
    f32x4 acc[4];
    #pragma unroll
    for (int nt = 0; nt < 4; ++nt) acc[nt] = vzero;
    #pragma unroll
    for (int s = 0; s < 8; ++s) {
      #pragma unroll
      for (int nt = 0; nt < 4; ++nt) {
        bf16x8 b = *(const bf16x8*)&buf[(nt * 8 + s) * 512 + ln * 8];
        acc[nt] = mfma16(af[s], b, acc[nt]);
      }
    }
    #pragma unroll
    for (int nt = 0; nt < 4; ++nt) {
      const float bias = bo[c * 64 + nt * 16 + lr];
      #pragma unroll
      for (int reg = 0; reg < 4; ++reg)
        sTw[(lq * 4 + reg) * 68 + nt * 16 + lr] = acc[nt][reg] + bias;
    }
    #pragma unroll
    for (int it = 0; it < 4; ++it) {
      const int gi = it * 4 + g4;
      f32x4 vv = *(const f32x4*)&sTw[r4 * 68 + gi * 4];
      float4* xp = (float4*)&X[((long)(mtile * 16 + r4)) * DIM + c * 64 + gi * 4];
      float4 old = *xp;
      old.x += vv[0]; old.y += vv[1]; old.z += vv[2]; old.w += vv[3];
      *xp = old;
      lsum += old.x + old.y + old.z + old.w;
      lss  += old.x * old.x + old.y * old.y + old.z * old.z + old.w * old.w;
      // ---- masked chain-pool (transient): reduce over the 8 rows of the
      // chain (lanes differing in r4 bits 0..2 = lane bits 2..4) ----
      float p0 = mkrow * old.x, p1 = mkrow * old.y;
      float p2 = mkrow * old.z, p3 = mkrow * old.w;
      #pragma unroll
      for (int off = 4; off <= 16; off <<= 1) {
        p0 += __shfl_xor(p0, off); p1 += __shfl_xor(p1, off);
        p2 += __shfl_xor(p2, off); p3 += __shfl_xor(p3, off);
      }
      if ((r4 & 7) == 0) {
        float4 ps = make_float4(p0, p1, p2, p3);
        *(float4*)&Xpool[(long)pch * DIM + c * 64 + gi * 4] = ps;
      }
    }
    __syncthreads();
  }
  // ---- fused LN2: lanes 4*r4..4*r4+3 hold partials of row r4 ----
  lsum += __shfl_xor(lsum, 1); lss += __shfl_xor(lss, 1);
  lsum += __shfl_xor(lsum, 2); lss += __shfl_xor(lss, 2);
  const float mu = lsum * (1.f / 256.f);
  const float rstd = rsqrtf(lss * (1.f / 256.f) - mu * mu + 1e-5f);
  const int row = mtile * 16 + r4;
  #pragma unroll
  for (int i = 0; i < 8; ++i) {
    const int q = i * 4 + g4;                // col-group 0..31
    const float4 x0 = *(const float4*)&X[(long)row * DIM + q * 8];
    const float4 x1 = *(const float4*)&X[(long)row * DIM + q * 8 + 4];
    const float4 g0 = *(const float4*)&ln2g[q * 8];
    const float4 g1 = *(const float4*)&ln2g[q * 8 + 4];
    const float4 b0 = *(const float4*)&ln2b[q * 8];
    const float4 b1 = *(const float4*)&ln2b[q * 8 + 4];
    u16x8 o;
    o[0] = f2bf((x0.x - mu) * rstd * g0.x + b0.x);
    o[1] = f2bf((x0.y - mu) * rstd * g0.y + b0.y);
    o[2] = f2bf((x0.z - mu) * rstd * g0.z + b0.z);
    o[3] = f2bf((x0.w - mu) * rstd * g0.w + b0.w);
    o[4] = f2bf((x1.x - mu) * rstd * g1.x + b1.x);
    o[5] = f2bf((x1.y - mu) * rstd * g1.y + b1.y);
    o[6] = f2bf((x1.z - mu) * rstd * g1.z + b1.z);
    o[7] = f2bf((x1.w - mu) * rstd * g1.w + b1.w);
    *(u16x8*)&H2p[((long)(mtile * 8 + (q >> 2)) * 64 + (q & 3) * 16 + r4) * 8] = o;
  }
}

// ---------------------------------------------------------------------------
// k_ff (r20 = r19): one f-HALF of pooled-gelu + FF2-through-pool. Block b:
// mb=b>>1 (16 chains), h=b&1 (ffcols h*512..+511). Two-pass structure:
//   pass 1 (16 iters): FF1 chunk (32 ffcols) -> gelu -> masked butterfly over
//   8 token-lanes -> G~ k-slice into Gs (16KB, A-frag layout).
//   pass 2: C[16ch x 256] = G~ @ w2[k-half] (w2 frags from L2) -> Pxg[h].
// LDS: w1 dbuf 32KB + Gs 16KB = 48KB -> 3 blocks/CU.
// ---------------------------------------------------------------------------
__global__ __launch_bounds__(256, 2) void k_ff(
    const unsigned short* __restrict__ H2p,
    const unsigned short* __restrict__ w1p, const unsigned short* __restrict__ w2p,
    const float* __restrict__ bff1, const int* __restrict__ NPICK,
    float* __restrict__ Pxg)
{
  __shared__ unsigned short buf[2][8192];   // 2 x 16KB w1 chunk double-buffer
  __shared__ unsigned short Gs[8192];       // 16KB pooled-gelu [kt 16][lane 64][8]
  const int tid = threadIdx.x;
  const int wv = tid >> 6, ln = tid & 63;
  const int lr = ln & 15, lq = ln >> 4;
  const int mb = blockIdx.x >> 1;           // m-block: 16 chains
  const int h  = blockIdx.x & 1;            // f-half
  const int mtA = mb * 8 + wv * 2, mtB = mtA + 1;
  const f32x4 vzero = {0.f, 0.f, 0.f, 0.f};

  // token-lane mask: lane's token = ln&7; chain-in-mtile = (ln>>3)&1
  const int sub = (ln >> 3) & 1;
  const int npcAl = NPICK[mtA * 2 + sub];
  const int npcBl = NPICK[mtB * 2 + sub];
  const float mTA = ((ln & 7) < npcAl) ? 1.f : 0.f;
  const float mTB = ((ln & 7) < npcBl) ? 1.f : 0.f;
  const int chA = wv * 4 + sub;             // block-local chain ids
  const int chB = wv * 4 + 2 + sub;

  // hoist token A-fragments (B-operand of FF1): 16 x bf16x8 = 64 VGPR
  bf16x8 afA[8], afB[8];
  #pragma unroll
  for (int s = 0; s < 8; ++s) {
    afA[s] = *(const bf16x8*)&H2p[((long)(mtA * 8 + s) * 64 + ln) * 8];
    afB[s] = *(const bf16x8*)&H2p[((long)(mtB * 8 + s) * 64 + ln) * 8];
  }

  // prologue: stage chunk h*16 -> buf[0]
  #pragma unroll
  for (int c = 0; c < 4; ++c) {
    const int off = (c * 256 + wv * 64) * 8;
    gload16(w1p + (long)(h * 16) * 8192 + off + ln * 8, &buf[0][off]);
  }
  __syncthreads();

  for (int i = 0; i < 16; ++i) {
    const int gi = h * 16 + i;               // global 32-ffcol chunk index
    const unsigned short* bcur = buf[i & 1];
    if (i < 15) {
      unsigned short* bnxt = buf[(i + 1) & 1];
      #pragma unroll
      for (int c = 0; c < 4; ++c) {
        const int off = (c * 256 + wv * 64) * 8;
        gload16(w1p + (long)(gi + 1) * 8192 + off + ln * 8, &bnxt[off]);
      }
    }
    // FF1: 32 ffcols (2 ntiles) x K=256; each w1f read feeds both groups
    f32x4 gaA[2], gaB[2];
    #pragma unroll
    for (int nt = 0; nt < 2; ++nt) { gaA[nt] = vzero; gaB[nt] = vzero; }
    #pragma unroll
    for (int s = 0; s < 8; ++s) {
      #pragma unroll
      for (int nt = 0; nt < 2; ++nt) {
        const bf16x8 w1f = *(const bf16x8*)&bcur[(nt * 8 + s) * 512 + ln * 8];
        gaA[nt] = mfma16(w1f, afA[s], gaA[nt]);
        gaB[nt] = mfma16(w1f, afB[s], gaB[nt]);
      }
    }
    // gelu + token mask + butterfly-pool over 8 token lanes
    float sA[2][4], sB[2][4];
    #pragma unroll
    for (int nt = 0; nt < 2; ++nt) {
      const float4 b4 = *(const float4*)&bff1[gi * 32 + nt * 16 + lq * 4];
      sA[nt][0] = rsum8(gelu_fast(gaA[nt][0] + b4.x) * mTA);
      sA[nt][1] = rsum8(gelu_fast(gaA[nt][1] + b4.y) * mTA);
      sA[nt][2] = rsum8(gelu_fast(gaA[nt][2] + b4.z) * mTA);
      sA[nt][3] = rsum8(gelu_fast(gaA[nt][3] + b4.w) * mTA);
      sB[nt][0] = rsum8(gelu_fast(gaB[nt][0] + b4.x) * mTB);
      sB[nt][1] = rsum8(gelu_fast(gaB[nt][1] + b4.y) * mTB);
      sB[nt][2] = rsum8(gelu_fast(gaB[nt][2] + b4.z) * mTB);
      sB[nt][3] = rsum8(gelu_fast(gaB[nt][3] + b4.w) * mTB);
    }
    // write G~ (one writer lane per 8-token group; values uniform in group)
    if ((ln & 7) == 0) {
      #pragma unroll
      for (int nt = 0; nt < 2; ++nt)
        #pragma unroll
        for (int reg = 0; reg < 4; ++reg) {
          const int r = lq * 4 + reg;            // ffcol within 16-col tile pair
          const int pos = (nt * 2 + (r >> 3)) * 16;
          const int e = r & 7;
          Gs[i * 512 + (chA + pos) * 8 + e] = f2bf(sA[nt][reg]);
          Gs[i * 512 + (chB + pos) * 8 + e] = f2bf(sB[nt][reg]);
        }
    }
    __syncthreads();   // drains vmcnt (next chunk ready); orders buf reuse
  }

  // ---- pass 2: C[ch 16][cols wv*64..+63] = G~ @ w2[k-half] ----
  f32x4 C[4];
  #pragma unroll
  for (int nt = 0; nt < 4; ++nt) C[nt] = vzero;
  for (int s = 0; s < 16; ++s) {
    const bf16x8 ag = *(const bf16x8*)&Gs[s * 512 + ln * 8];
    #pragma unroll
    for (int nt = 0; nt < 4; ++nt) {
      const bf16x8 w2f =
          *(const bf16x8*)&w2p[((long)((h * 16 + s) * 16 + wv * 4 + nt) * 64 + ln) * 8];
      C[nt] = mfma16(ag, w2f, C[nt]);
    }
  }
  // store partial C to Pxg[h] (each (ch,col) written by exactly one thread)
  #pragma unroll
  for (int nt = 0; nt < 4; ++nt) {
    #pragma unroll
    for (int reg = 0; reg < 4; ++reg) {
      const int m = lq * 4 + reg;              // block-local chain
      const int col = wv * 64 + nt * 16 + lr;
      Pxg[((long)h * 8192 + mb * 16 + m) * 256 + col] = C[nt][reg];
    }
  }
}

// ---------------------------------------------------------------------------
// k_fin (r20): Fp = (Xpool + C0 + C1)/np + bff2 ; count col ; zero pad.
// Xpool computed in k_oproj; k_fin no longer touches the 67MB X buffer.
// Traffic: Xpool 8.4MB + Pxg 16.8MB + Fp 5.2MB ~= 30MB.
// ---------------------------------------------------------------------------
__global__ __launch_bounds__(256) void k_fin(
    const float* __restrict__ Xpool, const float* __restrict__ Pxg,
    const float* __restrict__ bff2, const int* __restrict__ NPICK,
    const float* __restrict__ count, unsigned short* __restrict__ Fp)
{
  const int tid = threadIdx.x, blk = blockIdx.x;
  const int cl = tid >> 5, t32 = tid & 31;
  const int ch = blk * 8 + cl;
  const int np = NPICK[ch];
  const int rtile = ch >> 4, lrf = ch & 15;

  const float4 s0 = *(const float4*)&Xpool[(long)ch * 256 + t32 * 8];
  const float4 s1 = *(const float4*)&Xpool[(long)ch * 256 + t32 * 8 + 4];
  const float4 c00 = *(const float4*)&Pxg[((long)ch) * 256 + t32 * 8];
  const float4 c01 = *(const float4*)&Pxg[((long)ch) * 256 + t32 * 8 + 4];
  const float4 c10 = *(const float4*)&Pxg[((long)(8192 + ch)) * 256 + t32 * 8];
  const float4 c11 = *(const float4*)&Pxg[((long)(8192 + ch)) * 256 + t32 * 8 + 4];
  const float4 b0 = *(const float4*)&bff2[t32 * 8];
  const float4 b1 = *(const float4*)&bff2[t32 * 8 + 4];
  u16x8 o;
  if (np > 0) {
    const float inv = 1.f / (float)np;
    o[0] = f2bf((s0.x + c00.x + c10.x) * inv + b0.x);
    o[1] = f2bf((s0.y + c00.y + c10.y) * inv + b0.y);
    o[2] = f2bf((s0.z + c00.z + c10.z) * inv + b0.z);
    o[3] = f2bf((s0.w + c00.w + c10.w) * inv + b0.w);
    o[4] = f2bf((s1.x + c01.x + c11.x) * inv + b1.x);
    o[5] = f2bf((s1.y + c01.y + c11.y) * inv + b1.y);
    o[6] = f2bf((s1.z + c01.z + c11.z) * inv + b1.z);
    o[7] = f2bf((s1.w + c01.w + c11.w) * inv + b1.w);
  } else {
    #pragma unroll
    for (int j = 0; j < 8; ++j) o[j] = 0;
  }
  const int sgrp = t32 >> 2, lqf = t32 & 3;
  *(u16x8*)&Fp[((long)(rtile * 10 + sgrp) * 64 + lqf * 16 + lrf) * 8] = o;

  // tail: count column (grp 32) + zero pad (grp 33..39)
  if (tid < 64) {
    const int ch2 = blk * 8 + (tid >> 3);
    const int grp = 32 + (tid & 7);
    const int rt2 = ch2 >> 4, lr2 = ch2 & 15;
    u16x8 oz = {0,0,0,0,0,0,0,0};
    if (grp == 32) oz[0] = f2bf(log1pf(count[ch2]));
    const int s2 = grp >> 2, lq2 = grp & 3;
    *(u16x8*)&Fp[((long)(rt2 * 10 + s2) * 64 + lq2 * 16 + lr2) * 8] = oz;
  }
}

// ---------------------------------------------------------------------------
// k_headmlp: out += FF-quarter partial of gelu(F@wout1^T+b1)@wout2^T
// (+ bout2 from quarter 0). (r11 config — do not touch; r12's async variant
// spilled at the (512,4) 128-reg ceiling.)
// ---------------------------------------------------------------------------
__global__ __launch_bounds__(512, 4) void k_headmlp(
    const unsigned short* __restrict__ Fp,
    const unsigned short* __restrict__ wo1p, const unsigned short* __restrict__ wo2p,
    const float* __restrict__ bout1, const float* __restrict__ bout2,
    float* __restrict__ out)
{
  __shared__ unsigned short bufA[20480];   // 40 KB: wout1 f-chunk
  __shared__ unsigned short bufB[16384];   // 32 KB: wout2 f-chunk
  const int tid = threadIdx.x;
  const int fq = blockIdx.x & 3;
  const int mchunk = blockIdx.x >> 2;
  const int wv = tid >> 6, ln = tid & 63;
  const int lr = ln & 15, lq = ln >> 4;
  const int rtile = mchunk * 8 + wv;
  const f32x4 vzero = {0.f, 0.f, 0.f, 0.f};

  f32x4 oacc[16];
  #pragma unroll
  for (int nt = 0; nt < 16; ++nt) oacc[nt] = vzero;

  const int laneA = ((lq & 1) * 2) * 16 + lr;
  const int laneB = laneA + 16;
  const bool hi = (lq & 2) != 0;

  for (int it = 0; it < 4; ++it) {
    const int f = fq * 4 + it;
    __syncthreads();                         // previous iter's reads done
    #pragma unroll
    for (int i = 0; i < 5; ++i) {
      const int off = (i * 512 + wv * 64) * 8;
      gload16(wo1p + (long)f * 20480 + off + ln * 8, &bufA[off]);
    }
    #pragma unroll
    for (int i = 0; i < 4; ++i) {
      const int off = (i * 512 + wv * 64) * 8;
      gload16(wo2p + (long)f * 16384 + off + ln * 8, &bufB[off]);
    }
    __syncthreads();

    f32x4 ga[4];
    #pragma unroll
    for (int nt = 0; nt < 4; ++nt) ga[nt] = vzero;
    #pragma unroll
    for (int s = 0; s < 10; ++s) {
      const bf16x8 afs = *(const bf16x8*)&Fp[((long)(rtile * 10 + s) * 64 + ln) * 8];
      #pragma unroll
      for (int nt = 0; nt < 4; ++nt) {
        bf16x8 w1f = *(const bf16x8*)&bufA[(nt * 10 + s) * 512 + ln * 8];
        ga[nt] = mfma16(w1f, afs, ga[nt]);
      }
    }
    unsigned p0[4], p1[4];
    #pragma unroll
    for (int nt = 0; nt < 4; ++nt) {
      const float4 b4 = *(const float4*)&bout1[f * 64 + nt * 16 + lq * 4];
      const float g0 = gelu_fast(ga[nt][0] + b4.x);
      const float g1 = gelu_fast(ga[nt][1] + b4.y);
      const float g2 = gelu_fast(ga[nt][2] + b4.z);
      const float g3 = gelu_fast(ga[nt][3] + b4.w);
      p0[nt] = pack2bf(g0, g1);
      p1[nt] = pack2bf(g2, g3);
    }
    #pragma unroll
    for (int s2 = 0; s2 < 2; ++s2) {
      const unsigned a0 = (unsigned)__shfl((int)p0[2 * s2],     laneA, 64);
      const unsigned a1 = (unsigned)__shfl((int)p1[2 * s2],     laneA, 64);
      const unsigned a2 = (unsigned)__shfl((int)p0[2 * s2],     laneB, 64);
      const unsigned a3 = (unsigned)__shfl((int)p1[2 * s2],     laneB, 64);
      const unsigned c0 = (unsigned)__shfl((int)p0[2 * s2 + 1], laneA, 64);
      const unsigned c1 = (unsigned)__shfl((int)p1[2 * s2 + 1], laneA, 64);
      const unsigned c2 = (unsigned)__shfl((int)p0[2 * s2 + 1], laneB, 64);
      const unsigned c3 = (unsigned)__shfl((int)p1[2 * s2 + 1], laneB, 64);
      U4 uu;
      uu.u[0] = hi ? c0 : a0; uu.u[1] = hi ? c1 : a1;
      uu.u[2] = hi ? c2 : a2; uu.u[3] = hi ? c3 : a3;
      const bf16x8 gfrag = uu.v;
      #pragma unroll
      for (int nt = 0; nt < 16; ++nt) {
        bf16x8 w2f = *(const bf16x8*)&bufB[(s2 * 16 + nt) * 512 + ln * 8];
        oacc[nt] = mfma16(gfrag, w2f, oacc[nt]);
      }
    }
  }
  #pragma unroll
  for (int nt = 0; nt < 16; ++nt) {
    const int col = nt * 16 + lr;
    const float bias = (fq == 0) ? bout2[col] : 0.f;
    #pragma unroll
    for (int reg = 0; reg < 4; ++reg) {
      const int row = mchunk * 128 + wv * 16 + lq * 4 + reg;
      atomicAdd(&out[(long)row * DIM + col], oacc[nt][reg] + bias);
    }
  }
}

// ---------------------------------------------------------------------------
extern "C" void kernel_launch(void* const* d_in, const int* in_sizes, int n_in,
                              void* d_out, int out_size, void* d_ws, size_t ws_size,
                              hipStream_t stream) {
  (void)in_sizes; (void)n_in; (void)out_size; (void)ws_size;
  const float* v          = (const float*)d_in[0];
  const int*   batch_idx  = (const int*)  d_in[1];
  const int*   mask       = (const int*)  d_in[2];
  const float* count      = (const float*)d_in[3];
  const float* rank       = (const float*)d_in[4];
  const float* pe         = (const float*)d_in[5];
  const float* w_qkv      = (const float*)d_in[6];
  const float* b_qkv      = (const float*)d_in[7];
  const float* w_o        = (const float*)d_in[8];
  const float* b_o        = (const float*)d_in[9];
  const float* ln1g       = (const float*)d_in[10];
  const float* ln1b       = (const float*)d_in[11];
  const float* ln2g       = (const float*)d_in[12];
  const float* ln2b       = (const float*)d_in[13];
  const float* w_ff1      = (const float*)d_in[14];
  const float* b_ff1      = (const float*)d_in[15];
  const float* w_ff2      = (const float*)d_in[16];
  const float* b_ff2      = (const float*)d_in[17];
  const float* w_out1     = (const float*)d_in[18];
  const float* b_out1     = (const float*)d_in[19];
  const float* w_out2     = (const float*)d_in[20];
  const float* b_out2     = (const float*)d_in[21];
  float* out = (float*)d_out;

  char* ws = (char*)d_ws;
  float*          X     = (float*)ws;                              // 67,108,864
  unsigned short* H1p   = (unsigned short*)(ws + 67108864);        // 33,554,432
  unsigned short* Op    = H1p;                                     // alias: H1p dead after k_qkv
  float*          Pxg   = (float*)(ws + 67108864);                 // alias: Op dead after k_oproj (16.8MB)
  unsigned short* QKVp  = (unsigned short*)(ws + 100663296);       // 100,663,296 (65536x768 bf16)
  unsigned short* H2p   = QKVp;                                    // alias: QKVp dead after k_attn
  unsigned short* Fp    = (unsigned short*)(ws + 134217728);       // alias inside QKVp region
  float*          Xpool = (float*)(ws + 150994944);                // 8,388,608 (dead QKVp tail; live k_oproj->k_fin)
  int*            NPICK = (int*)(ws + 201326592);                  //     32,768
  unsigned short* wq_bf   = (unsigned short*)(ws + 201359360);     //    393,216
  unsigned short* wo_bf   = (unsigned short*)(ws + 201752576);     //    131,072
  unsigned short* wff1_bf = (unsigned short*)(ws + 201883648);     //    524,288
  unsigned short* wff2_bf = (unsigned short*)(ws + 202407936);     //    524,288 (k-major)
  unsigned short* wo1_bf  = (unsigned short*)(ws + 202932224);     //    655,360 (n-major, f-chunked)
  unsigned short* wo2_bf  = (unsigned short*)(ws + 203587584);     //    524,288 (k-major) -> end 204,111,872

  k_prep<<<PREP_GROUPS / 256, 256, 0, stream>>>(
      w_qkv, w_o, w_ff1, w_ff2, w_out1, w_out2,
      wq_bf, wo_bf, wff1_bf, wff2_bf, wo1_bf, wo2_bf);

  k_sel<<<8192, 256, 0, stream>>>(v, batch_idx, mask, rank, pe,
                                  ln1g, ln1b, X, H1p, NPICK);

  k_qkv<<<512, 512, 0, stream>>>(H1p, QKVp, wq_bf, b_qkv);

  k_attn<<<2048, 128, 0, stream>>>(QKVp, NPICK, Op);

  k_oproj<<<512, 512, 0, stream>>>(Op, X, wo_bf, b_o, ln2g, ln2b, H2p,
                                   NPICK, Xpool);

  k_ff<<<1024, 256, 0, stream>>>(H2p, wff1_bf, wff2_bf, b_ff1, NPICK, Pxg);

  k_fin<<<1024, 256, 0, stream>>>(Xpool, Pxg, b_ff2, NPICK, count, Fp);

  hipMemsetAsync(out, 0, (size_t)8192 * 256 * sizeof(float), stream);

  k_headmlp<<<256, 512, 0, stream>>>(Fp, wo1_bf, wo2_bf, b_out1, b_out2, out);
}

// Round 10
// 509.648 us; speedup vs baseline: 1.0258x; 1.0258x over previous
//
#include <hip/hip_runtime.h>

// ============================================================================
// TransformerSubsetAggregator on MI355X (gfx950) — round 21
// vs r20 (522.8, regression): Xpool-in-k_oproj put 192 cross-lane shuffles
// per thread in the hot loop (DS pipe) — cost > k_fin's savings. REVERTED to
// r19's k_oproj/k_fin (513.9 baseline). This round: launch consolidation,
// zero algorithmic risk — (1) k_prep merged into k_sel as 672 extra blocks
// (independent work, completes within the dispatch, before k_qkv); (2)
// memset(out) merged into k_fin (runs right before k_headmlp, the only
// consumer). 9 -> 7 dispatches, ~2 drain+launch gaps removed. All compute
// kernels byte-identical to r19.
// Pipeline: k_sel(+prep,+LN1->H1p) | k_qkv | k_attn | k_oproj(+LN2) |
//           k_ff x2 halves(->Pxg) | k_fin(+out=0,->Fp) | k_headmlp
// ============================================================================

#define DIM   256
#define LSEQ  128
#define KTOK  8

typedef __bf16 bf16x8 __attribute__((ext_vector_type(8)));
typedef float  f32x4  __attribute__((ext_vector_type(4)));
typedef unsigned short u16x8 __attribute__((ext_vector_type(8)));

__device__ __forceinline__ f32x4 mfma16(bf16x8 a, bf16x8 b, f32x4 c) {
  // D[m][n] = sum_k A[m][k]B[n][k]; lane map (both ops): idx=lane&15,
  // k=(lane>>4)*8+j. D: col(lane&15)=n, row=(lane>>4)*4+reg=m.
  return __builtin_amdgcn_mfma_f32_16x16x32_bf16(a, b, c, 0, 0, 0);
}

// HW RNE f32->bf16 (v_cvt; compiler pairs adjacent ones into v_cvt_pk_bf16_f32)
__device__ __forceinline__ unsigned short f2bf(float f) {
  union { __bf16 h; unsigned short u; } cv;
  cv.h = (__bf16)f;
  return cv.u;
}

__device__ __forceinline__ unsigned pack2bf(float a, float b) {
  union { __bf16 h2[2]; unsigned u; } cv;
  cv.h2[0] = (__bf16)a; cv.h2[1] = (__bf16)b;
  return cv.u;
}

// tanh-form gelu (~10 VALU ops); dev from exact ~1e-3 << bf16 rounding.
__device__ __forceinline__ float gelu_fast(float x) {
  const float x2 = x * x;
  const float y = x * __builtin_fmaf(0.0356774081f, x2, 0.7978845608f);
  const float e = __expf(2.f * y);
  const float r = __builtin_amdgcn_rcpf(e + 1.f);
  const float t = __builtin_fmaf(-2.f, r, 1.f);       // tanh(y)
  return 0.5f * x * (1.f + t);
}

// butterfly sum over the 8 token-lanes (lane bits 0..2)
__device__ __forceinline__ float rsum8(float v) {
  v += __shfl_xor(v, 1);
  v += __shfl_xor(v, 2);
  v += __shfl_xor(v, 4);
  return v;
}

union U4 { unsigned u[4]; bf16x8 v; };

// ---- async global->LDS, 16B/lane; lds base wave-uniform, HW adds lane*16.
__device__ __forceinline__ void gload16(const unsigned short* g, unsigned short* lds_uniform) {
  auto gp = reinterpret_cast<const __attribute__((address_space(1))) unsigned*>(
      reinterpret_cast<uintptr_t>(g));
  auto lp = reinterpret_cast<__attribute__((address_space(3))) unsigned*>(
      (unsigned)reinterpret_cast<uintptr_t>(lds_uniform));
  __builtin_amdgcn_global_load_lds(gp, lp, 16, 0, 0);
}

// ---- 32KB chunk staging: register prefetch + LDS commit (512-thr kernels)
struct Stage32 { u16x8 r[4]; };
__device__ __forceinline__ void stage_load(Stage32& st, const unsigned short* __restrict__ g, int tid) {
  #pragma unroll
  for (int i = 0; i < 4; ++i) st.r[i] = *(const u16x8*)&g[(tid + i * 512) * 8];
}
__device__ __forceinline__ void stage_commit(const Stage32& st, unsigned short* l, int tid) {
  #pragma unroll
  for (int i = 0; i < 4; ++i) *(u16x8*)&l[(tid + i * 512) * 8] = st.r[i];
}

// ---------------------------------------------------------------------------
// weight pack helpers (used by the prep branch merged into k_sel)
// ---------------------------------------------------------------------------
__device__ __forceinline__ void pack_region(
    const float* __restrict__ src, unsigned short* __restrict__ dst,
    int g, int KC, int Ksrc, int Klim)
{
  const int ln = g & 63;
  const int t = g >> 6;
  const int s = t % KC;
  const int ntile = t / KC;
  const int row = ntile * 16 + (ln & 15);
  const int c0 = s * 32 + (ln >> 4) * 8;
  u16x8 o;
  #pragma unroll
  for (int j = 0; j < 8; ++j) {
    float val = (c0 + j < Klim) ? src[(long)row * Ksrc + c0 + j] : 0.f;
    o[j] = f2bf(val);
  }
  *(u16x8*)&dst[(long)g * 8] = o;
}

__device__ __forceinline__ void pack_region_kmaj(
    const float* __restrict__ src, unsigned short* __restrict__ dst,
    int g, int NT, int Ksrc)
{
  const int ln = g & 63;
  const int t = g >> 6;
  const int ntile = t % NT;
  const int s = t / NT;
  const int row = ntile * 16 + (ln & 15);
  const int c0 = s * 32 + (ln >> 4) * 8;
  u16x8 o;
  #pragma unroll
  for (int j = 0; j < 8; ++j) o[j] = f2bf(src[(long)row * Ksrc + c0 + j]);
  *(u16x8*)&dst[(long)g * 8] = o;
}

#define PREP_BLOCKS 672   // 172032 groups / 256

// ---------------------------------------------------------------------------
// k_sel: blocks 0..8191 = top-8 select + gather + LN1 (r19 logic unchanged);
// blocks 8192..8863 = weight packing (was k_prep — independent, merged to
// drop one dispatch; completes within this dispatch, before k_qkv).
// ---------------------------------------------------------------------------
__global__ __launch_bounds__(256) void k_sel(
    const float* __restrict__ v, const int* __restrict__ batch_idx,
    const int* __restrict__ mask, const float* __restrict__ rank_scores,
    const float* __restrict__ pos_embed,
    const float* __restrict__ ln1g, const float* __restrict__ ln1b,
    float* __restrict__ X, unsigned short* __restrict__ H1p,
    int* __restrict__ NPICK,
    const float* __restrict__ wqkv, const float* __restrict__ wo,
    const float* __restrict__ wff1, const float* __restrict__ wff2,
    const float* __restrict__ wout1, const float* __restrict__ wout2,
    unsigned short* __restrict__ oq, unsigned short* __restrict__ oo,
    unsigned short* __restrict__ of1, unsigned short* __restrict__ of2,
    unsigned short* __restrict__ oo1, unsigned short* __restrict__ oo2)
{
  if (blockIdx.x >= 8192) {                  // ---- prep branch ----
    int g = (blockIdx.x - 8192) * 256 + threadIdx.x;
    if (g < 24576) { pack_region(wqkv, oq, g, 8, 256, 256); return; }     // n-major
    g -= 24576;
    if (g < 8192)  { pack_region(wo, oo, g, 8, 256, 256); return; }       // n-major
    g -= 8192;
    if (g < 32768) { pack_region(wff1, of1, g, 8, 256, 256); return; }    // n-major (f-chunked)
    g -= 32768;
    if (g < 32768) { pack_region_kmaj(wff2, of2, g, 16, 1024); return; }  // k-major
    g -= 32768;
    if (g < 40960) { pack_region(wout1, oo1, g, 10, 257, 257); return; }  // n-major (f-chunked)
    g -= 40960;
    if (g < 32768) { pack_region_kmaj(wout2, oo2, g, 16, 1024); }         // k-major
    return;
  }

  const int c = blockIdx.x;
  const int tid = threadIdx.x;
  __shared__ int s_mem[KTOK];
  __shared__ int s_np;

  if (tid < 64) {
    const int l = tid;
    unsigned long long key[2];
    #pragma unroll
    for (int t = 0; t < 2; ++t) {
      int p = l + 64 * t;
      int mk = mask[c * LSEQ + p];
      float s = rank_scores[c * LSEQ + p];
      unsigned u = __float_as_uint(s);
      u = (u & 0x80000000u) ? ~u : (u | 0x80000000u);
      unsigned long long kk =
          ((unsigned long long)u << 32) | (unsigned long long)(0xFFFFFFFFu - (unsigned)p);
      key[t] = mk ? kk : 0ull;
    }
    int w[KTOK];
    #pragma unroll
    for (int r = 0; r < KTOK; ++r) w[r] = 0x7FFFFFFF;
    int np = 0;
    for (int r = 0; r < KTOK; ++r) {
      unsigned long long best = key[0] > key[1] ? key[0] : key[1];
      for (int off = 32; off > 0; off >>= 1) {
        unsigned long long o = __shfl_xor(best, off, 64);
        if (o > best) best = o;
      }
      if (best == 0ull) break;
      int idx = (int)(0xFFFFFFFFu - (unsigned)(best & 0xFFFFFFFFull));
      w[np++] = idx;
      if (key[0] == best) key[0] = 0ull;
      if (key[1] == best) key[1] = 0ull;
    }
    #pragma unroll
    for (int a = 0; a < KTOK - 1; ++a)
      #pragma unroll
      for (int b2 = 0; b2 < KTOK - 1 - a; ++b2) {
        int x0 = w[b2], x1 = w[b2 + 1];
        w[b2] = min(x0, x1); w[b2 + 1] = max(x0, x1);
      }
    if (l < KTOK) s_mem[l] = (l < np) ? batch_idx[c * LSEQ + w[l]] : -1;
    if (l == 0) { s_np = np; NPICK[c] = np; }
  }
  __syncthreads();

  const int np = s_np;
  const int j = tid >> 5, q = tid & 31;     // 32 threads/token, 8 cols each
  const int r = s_mem[j];
  const float4* v4  = (const float4*)v;
  const float4* pe4 = (const float4*)pos_embed;
  float4* X4 = (float4*)X;

  float4 xv[2];                              // cols q*8 .. q*8+7
  #pragma unroll
  for (int rep = 0; rep < 2; ++rep) {
    const int f = 2 * q + rep;
    float4 pe = pe4[j * 64 + f];
    float4 val = make_float4(0.f, 0.f, 0.f, 0.f);
    if (j < np) val = v4[(long)r * 64 + f];
    xv[rep].x = val.x + pe.x; xv[rep].y = val.y + pe.y;
    xv[rep].z = val.z + pe.z; xv[rep].w = val.w + pe.w;
    X4[((long)c * KTOK + j) * 64 + f] = xv[rep];
  }
  float sum = 0.f, ss = 0.f;
  #pragma unroll
  for (int rep = 0; rep < 2; ++rep) {
    sum += xv[rep].x + xv[rep].y + xv[rep].z + xv[rep].w;
    ss  += xv[rep].x * xv[rep].x + xv[rep].y * xv[rep].y
         + xv[rep].z * xv[rep].z + xv[rep].w * xv[rep].w;
  }
  #pragma unroll
  for (int off = 1; off <= 16; off <<= 1) {
    sum += __shfl_xor(sum, off); ss += __shfl_xor(ss, off);
  }
  const float mu = sum * (1.f / 256.f);
  const float var = ss * (1.f / 256.f) - mu * mu;
  const float rstd = rsqrtf(var + 1e-5f);
  const int t = c * KTOK + j;
  const int mtile = t >> 4, lr = t & 15;
  const int s = q >> 2, lq = q & 3;
  u16x8 o;
  const int col = q * 8;
  o[0] = f2bf((xv[0].x - mu) * rstd * ln1g[col + 0] + ln1b[col + 0]);
  o[1] = f2bf((xv[0].y - mu) * rstd * ln1g[col + 1] + ln1b[col + 1]);
  o[2] = f2bf((xv[0].z - mu) * rstd * ln1g[col + 2] + ln1b[col + 2]);
  o[3] = f2bf((xv[0].w - mu) * rstd * ln1g[col + 3] + ln1b[col + 3]);
  o[4] = f2bf((xv[1].x - mu) * rstd * ln1g[col + 4] + ln1b[col + 4]);
  o[5] = f2bf((xv[1].y - mu) * rstd * ln1g[col + 5] + ln1b[col + 5]);
  o[6] = f2bf((xv[1].z - mu) * rstd * ln1g[col + 6] + ln1b[col + 6]);
  o[7] = f2bf((xv[1].w - mu) * rstd * ln1g[col + 7] + ln1b[col + 7]);
  *(u16x8*)&H1p[((long)(mtile * 8 + s) * 64 + lq * 16 + lr) * 8] = o;
}

// ---------------------------------------------------------------------------
// k_qkv: QKV GEMM, M=65536, N=768, K=256. 512 thr = 8 waves = 128 tokens.
// (r9 config — do not touch: r7/r10 launch-bound changes both spilled.)
// ---------------------------------------------------------------------------
__global__ __launch_bounds__(512, 4) void k_qkv(
    const unsigned short* __restrict__ H1p, unsigned short* __restrict__ QKVp,
    const unsigned short* __restrict__ wqp, const float* __restrict__ bqkv)
{
  __shared__ unsigned short buf[16384];      // 32 KB
  __shared__ unsigned short sT[8 * 16 * 72]; // per-wave 16 tok x 64 col (+8 pad)
  const int tid = threadIdx.x;
  const int wv = tid >> 6, ln = tid & 63;
  const int lr = ln & 15, lq = ln >> 4;
  const int mtile = blockIdx.x * 8 + wv;
  const f32x4 vzero = {0.f, 0.f, 0.f, 0.f};
  unsigned short* sTw = &sT[wv * 1152];

  bf16x8 af[8];
  #pragma unroll
  for (int s = 0; s < 8; ++s)
    af[s] = *(const bf16x8*)&H1p[((long)(mtile * 8 + s) * 64 + ln) * 8];

  Stage32 st;
  stage_load(st, wqp, tid);
  for (int c = 0; c < 12; ++c) {
    stage_commit(st, buf, tid);
    __syncthreads();
    if (c < 11) stage_load(st, wqp + (c + 1) * 16384, tid);
    f32x4 acc[4];
    #pragma unroll
    for (int nt = 0; nt < 4; ++nt) acc[nt] = vzero;
    #pragma unroll
    for (int s = 0; s < 8; ++s) {
      #pragma unroll
      for (int nt = 0; nt < 4; ++nt) {
        bf16x8 b = *(const bf16x8*)&buf[(nt * 8 + s) * 512 + ln * 8];
        acc[nt] = mfma16(af[s], b, acc[nt]);
      }
    }
    #pragma unroll
    for (int nt = 0; nt < 4; ++nt) {
      const float bias = bqkv[c * 64 + nt * 16 + lr];
      #pragma unroll
      for (int reg = 0; reg < 4; ++reg)
        sTw[(lq * 4 + reg) * 72 + nt * 16 + lr] = f2bf(acc[nt][reg] + bias);
    }
    const int r8 = ln >> 3, cg = ln & 7;
    #pragma unroll
    for (int h = 0; h < 2; ++h) {
      const int tok = h * 8 + r8;
      u16x8 vv = *(const u16x8*)&sTw[tok * 72 + cg * 8];
      *(u16x8*)&QKVp[((long)(mtile * 16 + tok)) * 768 + c * 64 + cg * 8] = vv;
    }
    __syncthreads();
  }
}

// ---------------------------------------------------------------------------
// k_attn: 4 chains (32 tokens)/block, 128 threads. Stages only K+V into LDS
// (33.3KB -> 4 blocks/CU); per-thread Q slice read directly from L2-warm
// QKVp into registers before the barrier.
// ---------------------------------------------------------------------------
#define SKV 520   // 512 + 8

__global__ __launch_bounds__(128) void k_attn(
    const unsigned short* __restrict__ QKVp, const int* __restrict__ NPICK,
    unsigned short* __restrict__ Op)
{
  __shared__ unsigned short sKV[32 * SKV];   // cols 0..255 = K, 256..511 = V
  __shared__ int s_np[4];
  const int tid = threadIdx.x;
  const int blk = blockIdx.x;
  if (tid < 4) s_np[tid] = NPICK[blk * 4 + tid];
  for (int i = tid; i < 2048; i += 128) {    // 16 x u16x8 per thread
    const int r = i >> 6, u = i & 63;
    *(u16x8*)&sKV[r * SKV + u * 8] =
        *(const u16x8*)&QKVp[((long)blk * 32 + r) * 768 + 256 + u * 8];
  }
  const int c = tid >> 5, hh = (tid >> 3) & 3, qi = tid & 7;
  const int qrow = c * 8 + qi;
  bf16x8 qv[8];                              // own Q slice: 128B from global
  #pragma unroll
  for (int dc = 0; dc < 8; ++dc)
    qv[dc] = *(const bf16x8*)&QKVp[((long)blk * 32 + qrow) * 768 + hh * 64 + dc * 8];
  __syncthreads();

  const int natt = max(1, s_np[c]);
  float sc[8];
  #pragma unroll
  for (int j = 0; j < 8; ++j) sc[j] = -1e30f;
  for (int j = 0; j < natt; ++j) {
    float d = 0.f;
    #pragma unroll
    for (int dc = 0; dc < 8; ++dc) {
      bf16x8 kv = *(const bf16x8*)&sKV[(c * 8 + j) * SKV + hh * 64 + dc * 8];
      #pragma unroll
      for (int e = 0; e < 8; ++e) d += (float)qv[dc][e] * (float)kv[e];
    }
    sc[j] = d * 0.125f;
  }
  float mx = -1e30f;
  #pragma unroll
  for (int j = 0; j < 8; ++j) mx = fmaxf(mx, sc[j]);
  float pr[8]; float ssum = 0.f;
  #pragma unroll
  for (int j = 0; j < 8; ++j) {
    float e = (j < natt) ? __expf(sc[j] - mx) : 0.f;
    pr[j] = e; ssum += e;
  }
  const float inv = 1.f / ssum;
  const int t = blk * 32 + qrow;
  const int mt = t >> 4, lrt = t & 15;
  #pragma unroll
  for (int dc = 0; dc < 8; ++dc) {
    float o8[8] = {0.f,0.f,0.f,0.f,0.f,0.f,0.f,0.f};
    for (int j = 0; j < natt; ++j) {
      const float pj = pr[j] * inv;
      bf16x8 vv = *(const bf16x8*)&sKV[(c * 8 + j) * SKV + 256 + hh * 64 + dc * 8];
      #pragma unroll
      for (int e = 0; e < 8; ++e) o8[e] += pj * (float)vv[e];
    }
    u16x8 o;
    #pragma unroll
    for (int e = 0; e < 8; ++e) o[e] = f2bf(o8[e]);
    const int s = hh * 2 + (dc >> 2), lqt = dc & 3;
    *(u16x8*)&Op[((long)(mt * 8 + s) * 64 + lqt * 16 + lrt) * 8] = o;
  }
}

// ---------------------------------------------------------------------------
// k_oproj: X += O @ wo^T + bo, FUSED LN2 -> H2p. (r19 config restored.)
// ---------------------------------------------------------------------------
__global__ __launch_bounds__(512, 4) void k_oproj(
    const unsigned short* __restrict__ Op, float* __restrict__ X,
    const unsigned short* __restrict__ wop, const float* __restrict__ bo,
    const float* __restrict__ ln2g, const float* __restrict__ ln2b,
    unsigned short* __restrict__ H2p)
{
  __shared__ unsigned short buf[16384];
  __shared__ float sTf[8 * 16 * 68];         // per-wave 16 tok x 64 col (+4 pad)
  const int tid = threadIdx.x;
  const int wv = tid >> 6, ln = tid & 63;
  const int lr = ln & 15, lq = ln >> 4;
  const int mtile = blockIdx.x * 8 + wv;
  const f32x4 vzero = {0.f, 0.f, 0.f, 0.f};
  float* sTw = &sTf[wv * 1088];

  bf16x8 af[8];
  #pragma unroll
  for (int s = 0; s < 8; ++s)
    af[s] = *(const bf16x8*)&Op[((long)(mtile * 8 + s) * 64 + ln) * 8];

  const int r4 = ln >> 2, g4 = ln & 3;
  float lsum = 0.f, lss = 0.f;               // partial LN sums for row r4

  Stage32 st;
  stage_load(st, wop, tid);
  for (int c = 0; c < 4; ++c) {
    stage_commit(st, buf, tid);
    __syncthreads();
    if (c < 3) stage_load(st, wop + (c + 1) * 16384, tid);
    f32x4 acc[4];
    #pragma unroll
    for (int nt = 0; nt < 4; ++nt) acc[nt] = vzero;
    #pragma unroll
    for (int s = 0; s < 8; ++s) {
      #pragma unroll
      for (int nt = 0; nt < 4; ++nt) {
        bf16x8 b = *(const bf16x8*)&buf[(nt * 8 + s) * 512 + ln * 8];
        acc[nt] = mfma16(af[s], b, acc[nt]);
      }
    }
    #pragma unroll
    for (int nt = 0; nt < 4; ++nt) {
      const float bias = bo[c * 64 + nt * 16 + lr];
      #pragma unroll
      for (int reg = 0; reg < 4; ++reg)
        sTw[(lq * 4 + reg) * 68 + nt * 16 + lr] = acc[nt][reg] + bias;
    }
    #pragma unroll
    for (int it = 0; it < 4; ++it) {
      const int gi = it * 4 + g4;
      f32x4 vv = *(const f32x4*)&sTw[r4 * 68 + gi * 4];
      float4* xp = (float4*)&X[((long)(mtile * 16 + r4)) * DIM + c * 64 + gi * 4];
      float4 old = *xp;
      old.x += vv[0]; old.y += vv[1]; old.z += vv[2]; old.w += vv[3];
      *xp = old;
      lsum += old.x + old.y + old.z + old.w;
      lss  += old.x * old.x + old.y * old.y + old.z * old.z + old.w * old.w;
    }
    __syncthreads();
  }
  // ---- fused LN2: lanes 4*r4..4*r4+3 hold partials of row r4 ----
  lsum += __shfl_xor(lsum, 1); lss += __shfl_xor(lss, 1);
  lsum += __shfl_xor(lsum, 2); lss += __shfl_xor(lss, 2);
  const float mu = lsum * (1.f / 256.f);
  const float rstd = rsqrtf(lss * (1.f / 256.f) - mu * mu + 1e-5f);
  const int row = mtile * 16 + r4;
  #pragma unroll
  for (int i = 0; i < 8; ++i) {
    const int q = i * 4 + g4;                // col-group 0..31
    const float4 x0 = *(const float4*)&X[(long)row * DIM + q * 8];
    const float4 x1 = *(const float4*)&X[(long)row * DIM + q * 8 + 4];
    const float4 g0 = *(const float4*)&ln2g[q * 8];
    const float4 g1 = *(const float4*)&ln2g[q * 8 + 4];
    const float4 b0 = *(const float4*)&ln2b[q * 8];
    const float4 b1 = *(const float4*)&ln2b[q * 8 + 4];
    u16x8 o;
    o[0] = f2bf((x0.x - mu) * rstd * g0.x + b0.x);
    o[1] = f2bf((x0.y - mu) * rstd * g0.y + b0.y);
    o[2] = f2bf((x0.z - mu) * rstd * g0.z + b0.z);
    o[3] = f2bf((x0.w - mu) * rstd * g0.w + b0.w);
    o[4] = f2bf((x1.x - mu) * rstd * g1.x + b1.x);
    o[5] = f2bf((x1.y - mu) * rstd * g1.y + b1.y);
    o[6] = f2bf((x1.z - mu) * rstd * g1.z + b1.z);
    o[7] = f2bf((x1.w - mu) * rstd * g1.w + b1.w);
    *(u16x8*)&H2p[((long)(mtile * 8 + (q >> 2)) * 64 + (q & 3) * 16 + r4) * 8] = o;
  }
}

// ---------------------------------------------------------------------------
// k_ff (r21 = r19): one f-HALF of pooled-gelu + FF2-through-pool. Block b:
// mb=b>>1 (16 chains), h=b&1 (ffcols h*512..+511). Two-pass structure:
//   pass 1 (16 iters): FF1 chunk (32 ffcols) -> gelu -> masked butterfly over
//   8 token-lanes -> G~ k-slice into Gs (16KB, A-frag layout).
//   pass 2: C[16ch x 256] = G~ @ w2[k-half] (w2 frags from L2) -> Pxg[h].
// LDS: w1 dbuf 32KB + Gs 16KB = 48KB -> 3 blocks/CU.
// ---------------------------------------------------------------------------
__global__ __launch_bounds__(256, 2) void k_ff(
    const unsigned short* __restrict__ H2p,
    const unsigned short* __restrict__ w1p, const unsigned short* __restrict__ w2p,
    const float* __restrict__ bff1, const int* __restrict__ NPICK,
    float* __restrict__ Pxg)
{
  __shared__ unsigned short buf[2][8192];   // 2 x 16KB w1 chunk double-buffer
  __shared__ unsigned short Gs[8192];       // 16KB pooled-gelu [kt 16][lane 64][8]
  const int tid = threadIdx.x;
  const int wv = tid >> 6, ln = tid & 63;
  const int lr = ln & 15, lq = ln >> 4;
  const int mb = blockIdx.x >> 1;           // m-block: 16 chains
  const int h  = blockIdx.x & 1;            // f-half
  const int mtA = mb * 8 + wv * 2, mtB = mtA + 1;
  const f32x4 vzero = {0.f, 0.f, 0.f, 0.f};

  // token-lane mask: lane's token = ln&7; chain-in-mtile = (ln>>3)&1
  const int sub = (ln >> 3) & 1;
  const int npcAl = NPICK[mtA * 2 + sub];
  const int npcBl = NPICK[mtB * 2 + sub];
  const float mTA = ((ln & 7) < npcAl) ? 1.f : 0.f;
  const float mTB = ((ln & 7) < npcBl) ? 1.f : 0.f;
  const int chA = wv * 4 + sub;             // block-local chain ids
  const int chB = wv * 4 + 2 + sub;

  // hoist token A-fragments (B-operand of FF1): 16 x bf16x8 = 64 VGPR
  bf16x8 afA[8], afB[8];
  #pragma unroll
  for (int s = 0; s < 8; ++s) {
    afA[s] = *(const bf16x8*)&H2p[((long)(mtA * 8 + s) * 64 + ln) * 8];
    afB[s] = *(const bf16x8*)&H2p[((long)(mtB * 8 + s) * 64 + ln) * 8];
  }

  // prologue: stage chunk h*16 -> buf[0]
  #pragma unroll
  for (int c = 0; c < 4; ++c) {
    const int off = (c * 256 + wv * 64) * 8;
    gload16(w1p + (long)(h * 16) * 8192 + off + ln * 8, &buf[0][off]);
  }
  __syncthreads();

  for (int i = 0; i < 16; ++i) {
    const int gi = h * 16 + i;               // global 32-ffcol chunk index
    const unsigned short* bcur = buf[i & 1];
    if (i < 15) {
      unsigned short* bnxt = buf[(i + 1) & 1];
      #pragma unroll
      for (int c = 0; c < 4; ++c) {
        const int off = (c * 256 + wv * 64) * 8;
        gload16(w1p + (long)(gi + 1) * 8192 + off + ln * 8, &bnxt[off]);
      }
    }
    // FF1: 32 ffcols (2 ntiles) x K=256; each w1f read feeds both groups
    f32x4 gaA[2], gaB[2];
    #pragma unroll
    for (int nt = 0; nt < 2; ++nt) { gaA[nt] = vzero; gaB[nt] = vzero; }
    #pragma unroll
    for (int s = 0; s < 8; ++s) {
      #pragma unroll
      for (int nt = 0; nt < 2; ++nt) {
        const bf16x8 w1f = *(const bf16x8*)&bcur[(nt * 8 + s) * 512 + ln * 8];
        gaA[nt] = mfma16(w1f, afA[s], gaA[nt]);
        gaB[nt] = mfma16(w1f, afB[s], gaB[nt]);
      }
    }
    // gelu + token mask + butterfly-pool over 8 token lanes
    float sA[2][4], sB[2][4];
    #pragma unroll
    for (int nt = 0; nt < 2; ++nt) {
      const float4 b4 = *(const float4*)&bff1[gi * 32 + nt * 16 + lq * 4];
      sA[nt][0] = rsum8(gelu_fast(gaA[nt][0] + b4.x) * mTA);
      sA[nt][1] = rsum8(gelu_fast(gaA[nt][1] + b4.y) * mTA);
      sA[nt][2] = rsum8(gelu_fast(gaA[nt][2] + b4.z) * mTA);
      sA[nt][3] = rsum8(gelu_fast(gaA[nt][3] + b4.w) * mTA);
      sB[nt][0] = rsum8(gelu_fast(gaB[nt][0] + b4.x) * mTB);
      sB[nt][1] = rsum8(gelu_fast(gaB[nt][1] + b4.y) * mTB);
      sB[nt][2] = rsum8(gelu_fast(gaB[nt][2] + b4.z) * mTB);
      sB[nt][3] = rsum8(gelu_fast(gaB[nt][3] + b4.w) * mTB);
    }
    // write G~ (one writer lane per 8-token group; values uniform in group)
    if ((ln & 7) == 0) {
      #pragma unroll
      for (int nt = 0; nt < 2; ++nt)
        #pragma unroll
        for (int reg = 0; reg < 4; ++reg) {
          const int r = lq * 4 + reg;            // ffcol within 16-col tile pair
          const int pos = (nt * 2 + (r >> 3)) * 16;
          const int e = r & 7;
          Gs[i * 512 + (chA + pos) * 8 + e] = f2bf(sA[nt][reg]);
          Gs[i * 512 + (chB + pos) * 8 + e] = f2bf(sB[nt][reg]);
        }
    }
    __syncthreads();   // drains vmcnt (next chunk ready); orders buf reuse
  }

  // ---- pass 2: C[ch 16][cols wv*64..+63] = G~ @ w2[k-half] ----
  f32x4 C[4];
  #pragma unroll
  for (int nt = 0; nt < 4; ++nt) C[nt] = vzero;
  for (int s = 0; s < 16; ++s) {
    const bf16x8 ag = *(const bf16x8*)&Gs[s * 512 + ln * 8];
    #pragma unroll
    for (int nt = 0; nt < 4; ++nt) {
      const bf16x8 w2f =
          *(const bf16x8*)&w2p[((long)((h * 16 + s) * 16 + wv * 4 + nt) * 64 + ln) * 8];
      C[nt] = mfma16(ag, w2f, C[nt]);
    }
  }
  // store partial C to Pxg[h] (each (ch,col) written by exactly one thread)
  #pragma unroll
  for (int nt = 0; nt < 4; ++nt) {
    #pragma unroll
    for (int reg = 0; reg < 4; ++reg) {
      const int m = lq * 4 + reg;              // block-local chain
      const int col = wv * 64 + nt * 16 + lr;
      Pxg[((long)h * 8192 + mb * 16 + m) * 256 + col] = C[nt][reg];
    }
  }
}

// ---------------------------------------------------------------------------
// k_fin (r21): Fp = (Xpool + C0 + C1)/np + bff2 ; count col ; zero pad;
// PLUS zeroing of 'out' (merged memset — k_headmlp is the only consumer and
// runs strictly after on the same stream). X-pool read from X as in r19.
// ---------------------------------------------------------------------------
__global__ __launch_bounds__(256) void k_fin(
    const float* __restrict__ X, const float* __restrict__ Pxg,
    const float* __restrict__ bff2, const int* __restrict__ NPICK,
    const float* __restrict__ count, unsigned short* __restrict__ Fp,
    float* __restrict__ out)
{
  const int tid = threadIdx.x, blk = blockIdx.x;

  // ---- merged memset: each block zeroes its 8KB slice of out ----
  {
    const float4 z = make_float4(0.f, 0.f, 0.f, 0.f);
    float4* op = (float4*)&out[(long)blk * 2048 + tid * 8];
    op[0] = z; op[1] = z;
  }

  const int cl = tid >> 5, t32 = tid & 31;
  const int ch = blk * 8 + cl;
  const int np = NPICK[ch];
  const int rtile = ch >> 4, lrf = ch & 15;

  float s[8] = {0.f,0.f,0.f,0.f,0.f,0.f,0.f,0.f};
  for (int j = 0; j < np; ++j) {             // uniform within the 32-thr group
    const float4 x0 = *(const float4*)&X[((long)ch * 8 + j) * 256 + t32 * 8];
    const float4 x1 = *(const float4*)&X[((long)ch * 8 + j) * 256 + t32 * 8 + 4];
    s[0] += x0.x; s[1] += x0.y; s[2] += x0.z; s[3] += x0.w;
    s[4] += x1.x; s[5] += x1.y; s[6] += x1.z; s[7] += x1.w;
  }
  const float4 c00 = *(const float4*)&Pxg[((long)ch) * 256 + t32 * 8];
  const float4 c01 = *(const float4*)&Pxg[((long)ch) * 256 + t32 * 8 + 4];
  const float4 c10 = *(const float4*)&Pxg[((long)(8192 + ch)) * 256 + t32 * 8];
  const float4 c11 = *(const float4*)&Pxg[((long)(8192 + ch)) * 256 + t32 * 8 + 4];
  const float4 b0 = *(const float4*)&bff2[t32 * 8];
  const float4 b1 = *(const float4*)&bff2[t32 * 8 + 4];
  u16x8 o;
  if (np > 0) {
    const float inv = 1.f / (float)np;
    o[0] = f2bf((s[0] + c00.x + c10.x) * inv + b0.x);
    o[1] = f2bf((s[1] + c00.y + c10.y) * inv + b0.y);
    o[2] = f2bf((s[2] + c00.z + c10.z) * inv + b0.z);
    o[3] = f2bf((s[3] + c00.w + c10.w) * inv + b0.w);
    o[4] = f2bf((s[4] + c01.x + c11.x) * inv + b1.x);
    o[5] = f2bf((s[5] + c01.y + c11.y) * inv + b1.y);
    o[6] = f2bf((s[6] + c01.z + c11.z) * inv + b1.z);
    o[7] = f2bf((s[7] + c01.w + c11.w) * inv + b1.w);
  } else {
    #pragma unroll
    for (int j = 0; j < 8; ++j) o[j] = 0;
  }
  const int sgrp = t32 >> 2, lqf = t32 & 3;
  *(u16x8*)&Fp[((long)(rtile * 10 + sgrp) * 64 + lqf * 16 + lrf) * 8] = o;

  // tail: count column (grp 32) + zero pad (grp 33..39)
  if (tid < 64) {
    const int ch2 = blk * 8 + (tid >> 3);
    const int grp = 32 + (tid & 7);
    const int rt2 = ch2 >> 4, lr2 = ch2 & 15;
    u16x8 oz = {0,0,0,0,0,0,0,0};
    if (grp == 32) oz[0] = f2bf(log1pf(count[ch2]));
    const int s2 = grp >> 2, lq2 = grp & 3;
    *(u16x8*)&Fp[((long)(rt2 * 10 + s2) * 64 + lq2 * 16 + lr2) * 8] = oz;
  }
}

// ---------------------------------------------------------------------------
// k_headmlp: out += FF-quarter partial of gelu(F@wout1^T+b1)@wout2^T
// (+ bout2 from quarter 0). (r11 config — do not touch; r12's async variant
// spilled at the (512,4) 128-reg ceiling.)
// ---------------------------------------------------------------------------
__global__ __launch_bounds__(512, 4) void k_headmlp(
    const unsigned short* __restrict__ Fp,
    const unsigned short* __restrict__ wo1p, const unsigned short* __restrict__ wo2p,
    const float* __restrict__ bout1, const float* __restrict__ bout2,
    float* __restrict__ out)
{
  __shared__ unsigned short bufA[20480];   // 40 KB: wout1 f-chunk
  __shared__ unsigned short bufB[16384];   // 32 KB: wout2 f-chunk
  const int tid = threadIdx.x;
  const int fq = blockIdx.x & 3;
  const int mchunk = blockIdx.x >> 2;
  const int wv = tid >> 6, ln = tid & 63;
  const int lr = ln & 15, lq = ln >> 4;
  const int rtile = mchunk * 8 + wv;
  const f32x4 vzero = {0.f, 0.f, 0.f, 0.f};

  f32x4 oacc[16];
  #pragma unroll
  for (int nt = 0; nt < 16; ++nt) oacc[nt] = vzero;

  const int laneA = ((lq & 1) * 2) * 16 + lr;
  const int laneB = laneA + 16;
  const bool hi = (lq & 2) != 0;

  for (int it = 0; it < 4; ++it) {
    const int f = fq * 4 + it;
    __syncthreads();                         // previous iter's reads done
    #pragma unroll
    for (int i = 0; i < 5; ++i) {
      const int off = (i * 512 + wv * 64) * 8;
      gload16(wo1p + (long)f * 20480 + off + ln * 8, &bufA[off]);
    }
    #pragma unroll
    for (int i = 0; i < 4; ++i) {
      const int off = (i * 512 + wv * 64) * 8;
      gload16(wo2p + (long)f * 16384 + off + ln * 8, &bufB[off]);
    }
    __syncthreads();

    f32x4 ga[4];
    #pragma unroll
    for (int nt = 0; nt < 4; ++nt) ga[nt] = vzero;
    #pragma unroll
    for (int s = 0; s < 10; ++s) {
      const bf16x8 afs = *(const bf16x8*)&Fp[((long)(rtile * 10 + s) * 64 + ln) * 8];
      #pragma unroll
      for (int nt = 0; nt < 4; ++nt) {
        bf16x8 w1f = *(const bf16x8*)&bufA[(nt * 10 + s) * 512 + ln * 8];
        ga[nt] = mfma16(w1f, afs, ga[nt]);
      }
    }
    unsigned p0[4], p1[4];
    #pragma unroll
    for (int nt = 0; nt < 4; ++nt) {
      const float4 b4 = *(const float4*)&bout1[f * 64 + nt * 16 + lq * 4];
      const float g0 = gelu_fast(ga[nt][0] + b4.x);
      const float g1 = gelu_fast(ga[nt][1] + b4.y);
      const float g2 = gelu_fast(ga[nt][2] + b4.z);
      const float g3 = gelu_fast(ga[nt][3] + b4.w);
      p0[nt] = pack2bf(g0, g1);
      p1[nt] = pack2bf(g2, g3);
    }
    #pragma unroll
    for (int s2 = 0; s2 < 2; ++s2) {
      const unsigned a0 = (unsigned)__shfl((int)p0[2 * s2],     laneA, 64);
      const unsigned a1 = (unsigned)__shfl((int)p1[2 * s2],     laneA, 64);
      const unsigned a2 = (unsigned)__shfl((int)p0[2 * s2],     laneB, 64);
      const unsigned a3 = (unsigned)__shfl((int)p1[2 * s2],     laneB, 64);
      const unsigned c0 = (unsigned)__shfl((int)p0[2 * s2 + 1], laneA, 64);
      const unsigned c1 = (unsigned)__shfl((int)p1[2 * s2 + 1], laneA, 64);
      const unsigned c2 = (unsigned)__shfl((int)p0[2 * s2 + 1], laneB, 64);
      const unsigned c3 = (unsigned)__shfl((int)p1[2 * s2 + 1], laneB, 64);
      U4 uu;
      uu.u[0] = hi ? c0 : a0; uu.u[1] = hi ? c1 : a1;
      uu.u[2] = hi ? c2 : a2; uu.u[3] = hi ? c3 : a3;
      const bf16x8 gfrag = uu.v;
      #pragma unroll
      for (int nt = 0; nt < 16; ++nt) {
        bf16x8 w2f = *(const bf16x8*)&bufB[(s2 * 16 + nt) * 512 + ln * 8];
        oacc[nt] = mfma16(gfrag, w2f, oacc[nt]);
      }
    }
  }
  #pragma unroll
  for (int nt = 0; nt < 16; ++nt) {
    const int col = nt * 16 + lr;
    const float bias = (fq == 0) ? bout2[col] : 0.f;
    #pragma unroll
    for (int reg = 0; reg < 4; ++reg) {
      const int row = mchunk * 128 + wv * 16 + lq * 4 + reg;
      atomicAdd(&out[(long)row * DIM + col], oacc[nt][reg] + bias);
    }
  }
}

// ---------------------------------------------------------------------------
extern "C" void kernel_launch(void* const* d_in, const int* in_sizes, int n_in,
                              void* d_out, int out_size, void* d_ws, size_t ws_size,
                              hipStream_t stream) {
  (void)in_sizes; (void)n_in; (void)out_size; (void)ws_size;
  const float* v          = (const float*)d_in[0];
  const int*   batch_idx  = (const int*)  d_in[1];
  const int*   mask       = (const int*)  d_in[2];
  const float* count      = (const float*)d_in[3];
  const float* rank       = (const float*)d_in[4];
  const float* pe         = (const float*)d_in[5];
  const float* w_qkv      = (const float*)d_in[6];
  const float* b_qkv      = (const float*)d_in[7];
  const float* w_o        = (const float*)d_in[8];
  const float* b_o        = (const float*)d_in[9];
  const float* ln1g       = (const float*)d_in[10];
  const float* ln1b       = (const float*)d_in[11];
  const float* ln2g       = (const float*)d_in[12];
  const float* ln2b       = (const float*)d_in[13];
  const float* w_ff1      = (const float*)d_in[14];
  const float* b_ff1      = (const float*)d_in[15];
  const float* w_ff2      = (const float*)d_in[16];
  const float* b_ff2      = (const float*)d_in[17];
  const float* w_out1     = (const float*)d_in[18];
  const float* b_out1     = (const float*)d_in[19];
  const float* w_out2     = (const float*)d_in[20];
  const float* b_out2     = (const float*)d_in[21];
  float* out = (float*)d_out;

  char* ws = (char*)d_ws;
  float*          X     = (float*)ws;                              // 67,108,864
  unsigned short* H1p   = (unsigned short*)(ws + 67108864);        // 33,554,432
  unsigned short* Op    = H1p;                                     // alias: H1p dead after k_qkv
  float*          Pxg   = (float*)(ws + 67108864);                 // alias: Op dead after k_oproj (16.8MB)
  unsigned short* QKVp  = (unsigned short*)(ws + 100663296);       // 100,663,296 (65536x768 bf16)
  unsigned short* H2p   = QKVp;                                    // alias: QKVp dead after k_attn
  unsigned short* Fp    = (unsigned short*)(ws + 134217728);       // alias inside QKVp region
  int*            NPICK = (int*)(ws + 201326592);                  //     32,768
  unsigned short* wq_bf   = (unsigned short*)(ws + 201359360);     //    393,216
  unsigned short* wo_bf   = (unsigned short*)(ws + 201752576);     //    131,072
  unsigned short* wff1_bf = (unsigned short*)(ws + 201883648);     //    524,288
  unsigned short* wff2_bf = (unsigned short*)(ws + 202407936);     //    524,288 (k-major)
  unsigned short* wo1_bf  = (unsigned short*)(ws + 202932224);     //    655,360 (n-major, f-chunked)
  unsigned short* wo2_bf  = (unsigned short*)(ws + 203587584);     //    524,288 (k-major) -> end 204,111,872

  k_sel<<<8192 + PREP_BLOCKS, 256, 0, stream>>>(
      v, batch_idx, mask, rank, pe, ln1g, ln1b, X, H1p, NPICK,
      w_qkv, w_o, w_ff1, w_ff2, w_out1, w_out2,
      wq_bf, wo_bf, wff1_bf, wff2_bf, wo1_bf, wo2_bf);

  k_qkv<<<512, 512, 0, stream>>>(H1p, QKVp, wq_bf, b_qkv);

  k_attn<<<2048, 128, 0, stream>>>(QKVp, NPICK, Op);

  k_oproj<<<512, 512, 0, stream>>>(Op, X, wo_bf, b_o, ln2g, ln2b, H2p);

  k_ff<<<1024, 256, 0, stream>>>(H2p, wff1_bf, wff2_bf, b_ff1, NPICK, Pxg);

  k_fin<<<1024, 256, 0, stream>>>(X, Pxg, b_ff2, NPICK, count, Fp, out);

  k_headmlp<<<256, 512, 0, stream>>>(Fp, wo1_bf, wo2_bf, b_out1, b_out2, out);
}